// Round 1
// baseline (807.810 us; speedup 1.0000x reference)
//
#include <hip/hip_runtime.h>
#include <stdint.h>

#define B_  4
#define S_  2048
#define D_  1024
#define H_  16
#define HD_ 64

typedef __attribute__((ext_vector_type(8))) short bf16x8;
typedef __attribute__((ext_vector_type(4))) short bf16x4;
typedef __attribute__((ext_vector_type(4))) float f32x4;

#define MFMA32(a, b, c) __builtin_amdgcn_mfma_f32_16x16x32_bf16(a, b, c, 0, 0, 0)

__device__ __forceinline__ unsigned short f2bf(float f) {
  union { float f; uint32_t u; } cv; cv.f = f;
  uint32_t x = cv.u;
  uint32_t r = (x + 0x7fffu + ((x >> 16) & 1u)) >> 16;  // RNE
  return (unsigned short)r;
}

__device__ __forceinline__ void gload_lds16(const unsigned short* g, unsigned short* l) {
  __builtin_amdgcn_global_load_lds((const __attribute__((address_space(1))) void*)g,
                                   (__attribute__((address_space(3))) void*)l, 16, 0, 0);
}

// ---------- prep: x fp32 -> bf16 ----------
__global__ void k_cast_x(const float* __restrict__ x, unsigned short* __restrict__ xb) {
  size_t i = ((size_t)blockIdx.x * 256 + threadIdx.x) * 8;
  float4 a = *(const float4*)(x + i);
  float4 b = *(const float4*)(x + i + 4);
  bf16x8 o;
  o[0] = (short)f2bf(a.x); o[1] = (short)f2bf(a.y);
  o[2] = (short)f2bf(a.z); o[3] = (short)f2bf(a.w);
  o[4] = (short)f2bf(b.x); o[5] = (short)f2bf(b.y);
  o[6] = (short)f2bf(b.z); o[7] = (short)f2bf(b.w);
  *(bf16x8*)(xb + i) = o;
}

// ---------- prep: Wq/Wk/Wv [H,D,HD] -> W1T [3072][1024] (n-major, k-contig) ----------
__global__ void k_wqkv_t(const float* __restrict__ Wq, const float* __restrict__ Wk,
                         const float* __restrict__ Wv, unsigned short* __restrict__ W1T) {
  __shared__ unsigned short tile[64][65];
  const float* W = (blockIdx.z == 0) ? Wq : (blockIdx.z == 1) ? Wk : Wv;
  int h = blockIdx.y;
  int d0 = blockIdx.x * 64;
  int tx = threadIdx.x & 63;
  int tg = threadIdx.x >> 6;
  const float* src = W + (size_t)h * (D_ * HD_) + (size_t)d0 * HD_;
#pragma unroll
  for (int r = 0; r < 16; ++r) {
    int dy = tg * 16 + r;
    tile[tx][dy] = f2bf(src[(size_t)dy * HD_ + tx]);  // tx = hd (coalesced read)
  }
  __syncthreads();
  unsigned short* dst = W1T + ((size_t)blockIdx.z * 1024 + (size_t)h * 64) * 1024 + d0;
#pragma unroll
  for (int r = 0; r < 16; ++r) {
    int hd = tg * 16 + r;
    dst[(size_t)hd * 1024 + tx] = tile[hd][tx];  // coalesced bf16 write
  }
}

// ---------- prep: Wp [D][D] -> WpT [n][k] ----------
__global__ void k_wp_t(const float* __restrict__ Wp, unsigned short* __restrict__ WpT) {
  __shared__ unsigned short tile[64][65];
  int n0 = blockIdx.x * 64, k0 = blockIdx.y * 64;
  int tx = threadIdx.x & 63;
  int tg = threadIdx.x >> 6;
#pragma unroll
  for (int r = 0; r < 16; ++r) {
    int ky = tg * 16 + r;
    tile[tx][ky] = f2bf(Wp[(size_t)(k0 + ky) * D_ + n0 + tx]);
  }
  __syncthreads();
#pragma unroll
  for (int r = 0; r < 16; ++r) {
    int ny = tg * 16 + r;
    WpT[(size_t)(n0 + ny) * D_ + k0 + tx] = tile[ny][tx];
  }
}

// ---------- GEMM1: C[8192][3072] = xb @ W1T^T ; scatter-store q,k,v_t ----------
__global__ __launch_bounds__(256) void k_gemm_qkv(const unsigned short* __restrict__ xb,
                                                  const unsigned short* __restrict__ W1T,
                                                  unsigned short* __restrict__ qb,
                                                  unsigned short* __restrict__ kb,
                                                  unsigned short* __restrict__ vt) {
  __shared__ __align__(16) unsigned short As[128 * 32];
  __shared__ __align__(16) unsigned short Bs[128 * 32];
  const int K = 1024;
  int tid = threadIdx.x;
  int lane = tid & 63;
  int w = tid >> 6;
  int c = lane & 15, g = lane >> 4;
  int wr = w >> 1, wc = w & 1;
  int m0 = blockIdx.y * 128;
  int n0 = blockIdx.x * 128;
  f32x4 acc[4][4];
#pragma unroll
  for (int m = 0; m < 4; ++m)
#pragma unroll
    for (int n = 0; n < 4; ++n) acc[m][n] = (f32x4){0.f, 0.f, 0.f, 0.f};

  int t0 = tid, t1 = tid + 256;
  const unsigned short* ga0 = xb + (size_t)(m0 + (t0 >> 2)) * K + 8 * (t0 & 3);
  const unsigned short* ga1 = xb + (size_t)(m0 + (t1 >> 2)) * K + 8 * (t1 & 3);
  const unsigned short* gb0 = W1T + (size_t)(n0 + (t0 >> 2)) * K + 8 * (t0 & 3);
  const unsigned short* gb1 = W1T + (size_t)(n0 + (t1 >> 2)) * K + 8 * (t1 & 3);

  for (int kk = 0; kk < K; kk += 32) {
    __syncthreads();
    gload_lds16(ga0 + kk, &As[t0 * 8]);
    gload_lds16(ga1 + kk, &As[t1 * 8]);
    gload_lds16(gb0 + kk, &Bs[t0 * 8]);
    gload_lds16(gb1 + kk, &Bs[t1 * 8]);
    __syncthreads();
    bf16x8 af[4], bfr[4];
#pragma unroll
    for (int m = 0; m < 4; ++m)
      af[m] = *(const bf16x8*)&As[(wr * 64 + m * 16 + c) * 32 + 8 * g];
#pragma unroll
    for (int n = 0; n < 4; ++n)
      bfr[n] = *(const bf16x8*)&Bs[(wc * 64 + n * 16 + c) * 32 + 8 * g];
#pragma unroll
    for (int m = 0; m < 4; ++m)
#pragma unroll
      for (int n = 0; n < 4; ++n) acc[m][n] = MFMA32(af[m], bfr[n], acc[m][n]);
  }

#pragma unroll
  for (int m = 0; m < 4; ++m)
#pragma unroll
    for (int n = 0; n < 4; ++n)
#pragma unroll
      for (int r = 0; r < 4; ++r) {
        int R = m0 + wr * 64 + m * 16 + 4 * g + r;
        int Cn = n0 + wc * 64 + n * 16 + c;
        unsigned short v = f2bf(acc[m][n][r]);
        int qkv = Cn >> 10;
        int h = (Cn >> 6) & 15;
        int hd = Cn & 63;
        int b = R >> 11;
        int s = R & 2047;
        size_t bh = (size_t)(b * 16 + h);
        if (qkv == 0)      qb[(bh * S_ + s) * HD_ + hd] = v;
        else if (qkv == 1) kb[(bh * S_ + s) * HD_ + hd] = v;
        else               vt[(bh * HD_ + hd) * S_ + s] = v;  // V transposed
      }
}

// ---------- flash attention: one wave per 16 q-rows, KV step = 32 ----------
__global__ __launch_bounds__(256) void k_attn(const unsigned short* __restrict__ qb,
                                              const unsigned short* __restrict__ kb,
                                              const unsigned short* __restrict__ vt,
                                              unsigned short* __restrict__ attn) {
  int lane = threadIdx.x & 63;
  int wid = blockIdx.x * 4 + (threadIdx.x >> 6);
  int qt = wid & 127;   // S/16 q-tiles
  int bh = wid >> 7;    // b*16+h
  int c = lane & 15, g = lane >> 4;
  int qbase = qt << 4;
  const unsigned short* qp = qb + ((size_t)bh * S_ + qbase) * HD_;
  const unsigned short* kp = kb + (size_t)bh * S_ * HD_;
  const unsigned short* vp = vt + (size_t)bh * HD_ * S_;
  // Q resident: lane holds Q[qbase+c][8g..8g+7] per 32-wide hd half
  bf16x8 qf0 = *(const bf16x8*)(qp + (size_t)c * HD_ + 8 * g);
  bf16x8 qf1 = *(const bf16x8*)(qp + (size_t)c * HD_ + 32 + 8 * g);
  const f32x4 fz = {0.f, 0.f, 0.f, 0.f};
  f32x4 oacc[4];
#pragma unroll
  for (int c4 = 0; c4 < 4; ++c4) oacc[c4] = fz;
  float m_old = -1e30f, lsum = 0.f;
  int nk = (qt + 2) >> 1;

  for (int kt = 0; kt < nk; ++kt) {
    int tb = kt << 5;
    // S^T = K·Q^T : A = K tile rows t, B = Q. D: row=t(4g+r), col=s(c)
    const unsigned short* kr0 = kp + (size_t)(tb + c) * HD_;
    const unsigned short* kr1 = kp + (size_t)(tb + 16 + c) * HD_;
    bf16x8 kf00 = *(const bf16x8*)(kr0 + 8 * g);
    bf16x8 kf01 = *(const bf16x8*)(kr0 + 32 + 8 * g);
    bf16x8 kf10 = *(const bf16x8*)(kr1 + 8 * g);
    bf16x8 kf11 = *(const bf16x8*)(kr1 + 32 + 8 * g);
    f32x4 st0 = MFMA32(kf00, qf0, fz);
    st0 = MFMA32(kf01, qf1, st0);
    f32x4 st1 = MFMA32(kf10, qf0, fz);
    st1 = MFMA32(kf11, qf1, st1);

    float sv[8];
#pragma unroll
    for (int r = 0; r < 4; ++r) { sv[r] = st0[r] * 0.125f; sv[4 + r] = st1[r] * 0.125f; }
    if (kt == nk - 1) {  // causal mask (only the diagonal 32-block needs it)
#pragma unroll
      for (int j = 0; j < 8; ++j) {
        int tgl = tb + ((j >> 2) << 4) + 4 * g + (j & 3);
        if (tgl > qbase + c) sv[j] = -1e30f;
      }
    }
    // row (s=c) max across regs + lane-groups
    float mx = sv[0];
#pragma unroll
    for (int j = 1; j < 8; ++j) mx = fmaxf(mx, sv[j]);
    mx = fmaxf(mx, __shfl_xor(mx, 16));
    mx = fmaxf(mx, __shfl_xor(mx, 32));
    float m_new = fmaxf(m_old, mx);
    float resc = __expf(m_old - m_new);
    float p[8], rs = 0.f;
#pragma unroll
    for (int j = 0; j < 8; ++j) { p[j] = __expf(sv[j] - m_new); rs += p[j]; }
    rs += __shfl_xor(rs, 16);
    rs += __shfl_xor(rs, 32);
    lsum = lsum * resc + rs;
    m_old = m_new;
    // broadcast rescale from softmax layout (s=c) to O layout (s=4g+r)
    float rb0 = __shfl(resc, 4 * g + 0);
    float rb1 = __shfl(resc, 4 * g + 1);
    float rb2 = __shfl(resc, 4 * g + 2);
    float rb3 = __shfl(resc, 4 * g + 3);
#pragma unroll
    for (int c4 = 0; c4 < 4; ++c4) {
      oacc[c4][0] *= rb0; oacc[c4][1] *= rb1; oacc[c4][2] *= rb2; oacc[c4][3] *= rb3;
    }
    // P -> bf16 A-frag (reg j=4*th+r pairs with V-frag reg j: same t)
    bf16x8 pa;
#pragma unroll
    for (int j = 0; j < 8; ++j) pa[j] = (short)f2bf(p[j]);
#pragma unroll
    for (int c4 = 0; c4 < 4; ++c4) {
      const unsigned short* vr = vp + (size_t)(c4 * 16 + c) * S_ + tb + 4 * g;
      bf16x4 v0 = *(const bf16x4*)(vr);        // t = tb+4g..+3
      bf16x4 v1 = *(const bf16x4*)(vr + 16);   // t = tb+16+4g..+3
      bf16x8 vf;
      vf[0] = v0[0]; vf[1] = v0[1]; vf[2] = v0[2]; vf[3] = v0[3];
      vf[4] = v1[0]; vf[5] = v1[1]; vf[6] = v1[2]; vf[7] = v1[3];
      oacc[c4] = MFMA32(pa, vf, oacc[c4]);
    }
  }
  float linv = 1.f / lsum;
  float lb0 = __shfl(linv, 4 * g + 0);
  float lb1 = __shfl(linv, 4 * g + 1);
  float lb2 = __shfl(linv, 4 * g + 2);
  float lb3 = __shfl(linv, 4 * g + 3);
  float lb[4] = {lb0, lb1, lb2, lb3};
  int b = bh >> 4, h = bh & 15;
  unsigned short* op = attn + ((size_t)b * S_ + qbase) * D_ + h * HD_;
#pragma unroll
  for (int c4 = 0; c4 < 4; ++c4)
#pragma unroll
    for (int r = 0; r < 4; ++r)
      op[(size_t)(4 * g + r) * D_ + c4 * 16 + c] = f2bf(oacc[c4][r] * lb[r]);
}

// ---------- GEMM2: out[8192][1024] = attn @ Wp + bp (fp32 out) ----------
__global__ __launch_bounds__(256) void k_gemm_out(const unsigned short* __restrict__ at,
                                                  const unsigned short* __restrict__ WpT,
                                                  const float* __restrict__ bp,
                                                  float* __restrict__ out) {
  __shared__ __align__(16) unsigned short As[128 * 32];
  __shared__ __align__(16) unsigned short Bs[128 * 32];
  const int K = 1024;
  int tid = threadIdx.x;
  int lane = tid & 63;
  int w = tid >> 6;
  int c = lane & 15, g = lane >> 4;
  int wr = w >> 1, wc = w & 1;
  int m0 = blockIdx.y * 128;
  int n0 = blockIdx.x * 128;
  f32x4 acc[4][4];
#pragma unroll
  for (int m = 0; m < 4; ++m)
#pragma unroll
    for (int n = 0; n < 4; ++n) acc[m][n] = (f32x4){0.f, 0.f, 0.f, 0.f};

  int t0 = tid, t1 = tid + 256;
  const unsigned short* ga0 = at + (size_t)(m0 + (t0 >> 2)) * K + 8 * (t0 & 3);
  const unsigned short* ga1 = at + (size_t)(m0 + (t1 >> 2)) * K + 8 * (t1 & 3);
  const unsigned short* gb0 = WpT + (size_t)(n0 + (t0 >> 2)) * K + 8 * (t0 & 3);
  const unsigned short* gb1 = WpT + (size_t)(n0 + (t1 >> 2)) * K + 8 * (t1 & 3);

  for (int kk = 0; kk < K; kk += 32) {
    __syncthreads();
    gload_lds16(ga0 + kk, &As[t0 * 8]);
    gload_lds16(ga1 + kk, &As[t1 * 8]);
    gload_lds16(gb0 + kk, &Bs[t0 * 8]);
    gload_lds16(gb1 + kk, &Bs[t1 * 8]);
    __syncthreads();
    bf16x8 af[4], bfr[4];
#pragma unroll
    for (int m = 0; m < 4; ++m)
      af[m] = *(const bf16x8*)&As[(wr * 64 + m * 16 + c) * 32 + 8 * g];
#pragma unroll
    for (int n = 0; n < 4; ++n)
      bfr[n] = *(const bf16x8*)&Bs[(wc * 64 + n * 16 + c) * 32 + 8 * g];
#pragma unroll
    for (int m = 0; m < 4; ++m)
#pragma unroll
      for (int n = 0; n < 4; ++n) acc[m][n] = MFMA32(af[m], bfr[n], acc[m][n]);
  }

#pragma unroll
  for (int m = 0; m < 4; ++m)
#pragma unroll
    for (int n = 0; n < 4; ++n)
#pragma unroll
      for (int r = 0; r < 4; ++r) {
        int R = m0 + wr * 64 + m * 16 + 4 * g + r;
        int Cn = n0 + wc * 64 + n * 16 + c;
        out[(size_t)R * D_ + Cn] = acc[m][n][r] + bp[Cn];
      }
}

extern "C" void kernel_launch(void* const* d_in, const int* in_sizes, int n_in,
                              void* d_out, int out_size, void* d_ws, size_t ws_size,
                              hipStream_t stream) {
  const float* x  = (const float*)d_in[0];
  const float* Wq = (const float*)d_in[1];
  const float* Wk = (const float*)d_in[2];
  const float* Wv = (const float*)d_in[3];
  const float* Wp = (const float*)d_in[4];
  const float* bp = (const float*)d_in[5];
  float* out = (float*)d_out;
  char* ws = (char*)d_ws;
  // workspace layout (72 MB total):
  unsigned short* xb  = (unsigned short*)(ws);                       // 16 MB (reused as attn out)
  unsigned short* w1t = (unsigned short*)(ws + (size_t)(16u << 20)); //  6 MB
  unsigned short* wpt = (unsigned short*)(ws + (size_t)(22u << 20)); //  2 MB
  unsigned short* qb  = (unsigned short*)(ws + (size_t)(24u << 20)); // 16 MB
  unsigned short* kb  = (unsigned short*)(ws + (size_t)(40u << 20)); // 16 MB
  unsigned short* vt  = (unsigned short*)(ws + (size_t)(56u << 20)); // 16 MB
  unsigned short* at  = xb;  // xb dead after gemm_qkv; reuse for attention output

  k_cast_x<<<dim3(4096), dim3(256), 0, stream>>>(x, xb);
  k_wqkv_t<<<dim3(16, 16, 3), dim3(256), 0, stream>>>(Wq, Wk, Wv, w1t);
  k_wp_t<<<dim3(16, 16), dim3(256), 0, stream>>>(Wp, wpt);
  k_gemm_qkv<<<dim3(24, 64), dim3(256), 0, stream>>>(xb, w1t, qb, kb, vt);
  k_attn<<<dim3(2048), dim3(256), 0, stream>>>(qb, kb, vt, at);
  k_gemm_out<<<dim3(8, 64), dim3(256), 0, stream>>>(at, wpt, bp, out);
}

// Round 2
// 260.959 us; speedup vs baseline: 3.0955x; 3.0955x over previous
//
#include <hip/hip_runtime.h>
#include <stdint.h>

#define B_  4
#define S_  2048
#define D_  1024
#define H_  16
#define HD_ 64

typedef __attribute__((ext_vector_type(8))) short bf16x8;
typedef __attribute__((ext_vector_type(4))) short bf16x4;
typedef __attribute__((ext_vector_type(4))) float f32x4;

#define MFMA32(a, b, c) __builtin_amdgcn_mfma_f32_16x16x32_bf16(a, b, c, 0, 0, 0)

__device__ __forceinline__ unsigned short f2bf(float f) {
  union { float f; uint32_t u; } cv; cv.f = f;
  uint32_t x = cv.u;
  uint32_t r = (x + 0x7fffu + ((x >> 16) & 1u)) >> 16;  // RNE
  return (unsigned short)r;
}

__device__ __forceinline__ void gload_lds16(const unsigned short* g, unsigned short* l) {
  __builtin_amdgcn_global_load_lds((const __attribute__((address_space(1))) void*)g,
                                   (__attribute__((address_space(3))) void*)l, 16, 0, 0);
}

// ---------- prep: x fp32 -> bf16 ----------
__global__ void k_cast_x(const float* __restrict__ x, unsigned short* __restrict__ xb) {
  size_t i = ((size_t)blockIdx.x * 256 + threadIdx.x) * 8;
  float4 a = *(const float4*)(x + i);
  float4 b = *(const float4*)(x + i + 4);
  bf16x8 o;
  o[0] = (short)f2bf(a.x); o[1] = (short)f2bf(a.y);
  o[2] = (short)f2bf(a.z); o[3] = (short)f2bf(a.w);
  o[4] = (short)f2bf(b.x); o[5] = (short)f2bf(b.y);
  o[6] = (short)f2bf(b.z); o[7] = (short)f2bf(b.w);
  *(bf16x8*)(xb + i) = o;
}

// ---------- prep: Wq/Wk/Wv [H,D,HD] -> W1T [3072][1024] (n-major, k-contig) ----------
__global__ void k_wqkv_t(const float* __restrict__ Wq, const float* __restrict__ Wk,
                         const float* __restrict__ Wv, unsigned short* __restrict__ W1T) {
  __shared__ unsigned short tile[64][65];
  const float* W = (blockIdx.z == 0) ? Wq : (blockIdx.z == 1) ? Wk : Wv;
  int h = blockIdx.y;
  int d0 = blockIdx.x * 64;
  int tx = threadIdx.x & 63;
  int tg = threadIdx.x >> 6;
  const float* src = W + (size_t)h * (D_ * HD_) + (size_t)d0 * HD_;
#pragma unroll
  for (int r = 0; r < 16; ++r) {
    int dy = tg * 16 + r;
    tile[tx][dy] = f2bf(src[(size_t)dy * HD_ + tx]);  // tx = hd (coalesced read)
  }
  __syncthreads();
  unsigned short* dst = W1T + ((size_t)blockIdx.z * 1024 + (size_t)h * 64) * 1024 + d0;
#pragma unroll
  for (int r = 0; r < 16; ++r) {
    int hd = tg * 16 + r;
    dst[(size_t)hd * 1024 + tx] = tile[hd][tx];  // coalesced bf16 write
  }
}

// ---------- prep: Wp [D][D] -> WpT [n][k] ----------
__global__ void k_wp_t(const float* __restrict__ Wp, unsigned short* __restrict__ WpT) {
  __shared__ unsigned short tile[64][65];
  int n0 = blockIdx.x * 64, k0 = blockIdx.y * 64;
  int tx = threadIdx.x & 63;
  int tg = threadIdx.x >> 6;
#pragma unroll
  for (int r = 0; r < 16; ++r) {
    int ky = tg * 16 + r;
    tile[tx][ky] = f2bf(Wp[(size_t)(k0 + ky) * D_ + n0 + tx]);
  }
  __syncthreads();
#pragma unroll
  for (int r = 0; r < 16; ++r) {
    int ny = tg * 16 + r;
    WpT[(size_t)(n0 + ny) * D_ + k0 + tx] = tile[ny][tx];
  }
}

// ---------- GEMM1: C[8192][3072] = xb @ W1T^T ; scatter-store q,k,v_t ----------
__global__ __launch_bounds__(256) void k_gemm_qkv(const unsigned short* __restrict__ xb,
                                                  const unsigned short* __restrict__ W1T,
                                                  unsigned short* __restrict__ qb,
                                                  unsigned short* __restrict__ kb,
                                                  unsigned short* __restrict__ vt) {
  __shared__ __align__(16) unsigned short As[128 * 32];
  __shared__ __align__(16) unsigned short Bs[128 * 32];
  const int K = 1024;
  int tid = threadIdx.x;
  int lane = tid & 63;
  int w = tid >> 6;
  int c = lane & 15, g = lane >> 4;
  int wr = w >> 1, wc = w & 1;
  int m0 = blockIdx.y * 128;
  int n0 = blockIdx.x * 128;
  f32x4 acc[4][4];
#pragma unroll
  for (int m = 0; m < 4; ++m)
#pragma unroll
    for (int n = 0; n < 4; ++n) acc[m][n] = (f32x4){0.f, 0.f, 0.f, 0.f};

  int t0 = tid, t1 = tid + 256;
  const unsigned short* ga0 = xb + (size_t)(m0 + (t0 >> 2)) * K + 8 * (t0 & 3);
  const unsigned short* ga1 = xb + (size_t)(m0 + (t1 >> 2)) * K + 8 * (t1 & 3);
  const unsigned short* gb0 = W1T + (size_t)(n0 + (t0 >> 2)) * K + 8 * (t0 & 3);
  const unsigned short* gb1 = W1T + (size_t)(n0 + (t1 >> 2)) * K + 8 * (t1 & 3);

  for (int kk = 0; kk < K; kk += 32) {
    __syncthreads();
    gload_lds16(ga0 + kk, &As[t0 * 8]);
    gload_lds16(ga1 + kk, &As[t1 * 8]);
    gload_lds16(gb0 + kk, &Bs[t0 * 8]);
    gload_lds16(gb1 + kk, &Bs[t1 * 8]);
    __syncthreads();
    bf16x8 af[4], bfr[4];
#pragma unroll
    for (int m = 0; m < 4; ++m)
      af[m] = *(const bf16x8*)&As[(wr * 64 + m * 16 + c) * 32 + 8 * g];
#pragma unroll
    for (int n = 0; n < 4; ++n)
      bfr[n] = *(const bf16x8*)&Bs[(wc * 64 + n * 16 + c) * 32 + 8 * g];
#pragma unroll
    for (int m = 0; m < 4; ++m)
#pragma unroll
      for (int n = 0; n < 4; ++n) acc[m][n] = MFMA32(af[m], bfr[n], acc[m][n]);
  }

#pragma unroll
  for (int m = 0; m < 4; ++m)
#pragma unroll
    for (int n = 0; n < 4; ++n)
#pragma unroll
      for (int r = 0; r < 4; ++r) {
        int R = m0 + wr * 64 + m * 16 + 4 * g + r;
        int Cn = n0 + wc * 64 + n * 16 + c;
        unsigned short v = f2bf(acc[m][n][r]);
        int qkv = Cn >> 10;
        int h = (Cn >> 6) & 15;
        int hd = Cn & 63;
        int b = R >> 11;
        int s = R & 2047;
        size_t bh = (size_t)(b * 16 + h);
        if (qkv == 0)      qb[(bh * S_ + s) * HD_ + hd] = v;
        else if (qkv == 1) kb[(bh * S_ + s) * HD_ + hd] = v;
        else               vt[(bh * HD_ + hd) * S_ + s] = v;  // V transposed
      }
}

// ---------- flash attention v2: 128 Q-rows/block (4 waves x 32), KV step 64,
// K/V staged in LDS (XOR-swizzled), XCD-aware block swizzle ----------
__global__ __launch_bounds__(256) void k_attn(const unsigned short* __restrict__ qb,
                                              const unsigned short* __restrict__ kb,
                                              const unsigned short* __restrict__ vt,
                                              unsigned short* __restrict__ attn) {
  __shared__ __align__(16) unsigned short Ks[64 * 64];
  __shared__ __align__(16) unsigned short Vs[64 * 64];
  int tid = threadIdx.x;
  int lane = tid & 63;
  int w = tid >> 6;
  int c = lane & 15, g = lane >> 4;
  // XCD swizzle: 1024 blocks, 8 XCDs -> XCD x gets bh [8x, 8x+8)  (K/V set = 4MB = L2)
  int swz = ((blockIdx.x & 7) << 7) | (blockIdx.x >> 3);
  int bh = swz >> 4;
  int qblk = swz & 15;
  int q0w = qblk * 128 + w * 32;  // this wave's first q row
  const unsigned short* qp = qb + ((size_t)bh * S_ + q0w) * HD_;
  const unsigned short* kp = kb + (size_t)bh * S_ * HD_;
  const unsigned short* vp = vt + (size_t)bh * HD_ * S_;

  // Q resident: qf[qs][half]: lane holds Q[q0w+qs*16+c][half*32+8g .. +8]
  bf16x8 qf[2][2];
#pragma unroll
  for (int qs = 0; qs < 2; ++qs)
#pragma unroll
    for (int h2 = 0; h2 < 2; ++h2)
      qf[qs][h2] = *(const bf16x8*)(qp + (size_t)(qs * 16 + c) * HD_ + h2 * 32 + 8 * g);

  const f32x4 fz = {0.f, 0.f, 0.f, 0.f};
  f32x4 oacc[4][2];
#pragma unroll
  for (int c4 = 0; c4 < 4; ++c4)
#pragma unroll
    for (int qs = 0; qs < 2; ++qs) oacc[c4][qs] = fz;
  float m[2] = {-1e30f, -1e30f};
  float l[2] = {0.f, 0.f};

  int nkb = 2 * qblk + 2;          // tiles the block stages (covers t < 128*qblk+128)
  int nkw = (q0w + 95) >> 6;       // tiles this wave computes

  for (int kt = 0; kt < nkb; ++kt) {
    int tb = kt << 6;
    __syncthreads();  // previous compute done before overwriting LDS
    {
      int i0 = tid, i1 = tid + 256;
      int r0 = i0 >> 3, ch0 = ((i0 & 7) ^ (r0 & 7)) << 3;  // inverse-swizzled src chunk
      int r1 = i1 >> 3, ch1 = ((i1 & 7) ^ (r1 & 7)) << 3;
      gload_lds16(kp + (size_t)(tb + r0) * HD_ + ch0, &Ks[i0 * 8]);
      gload_lds16(kp + (size_t)(tb + r1) * HD_ + ch1, &Ks[i1 * 8]);
      gload_lds16(vp + (size_t)r0 * S_ + tb + ch0, &Vs[i0 * 8]);
      gload_lds16(vp + (size_t)r1 * S_ + tb + ch1, &Vs[i1 * 8]);
    }
    __syncthreads();
    if (kt >= nkw) continue;  // idle wave still hits both barriers

    // ---- QK^T: S^T[t][q], t = tb + k4*16 + 4g + r, q = q0w + qs*16 + c ----
    f32x4 st[4][2];
#pragma unroll
    for (int k4 = 0; k4 < 4; ++k4) {
      int row = k4 * 16 + c;
      int rx = row & 7;
      bf16x8 a0 = *(const bf16x8*)&Ks[row * 64 + ((g ^ rx) << 3)];
      bf16x8 a1 = *(const bf16x8*)&Ks[row * 64 + (((4 + g) ^ rx) << 3)];
#pragma unroll
      for (int qs = 0; qs < 2; ++qs) {
        f32x4 t0 = MFMA32(a0, qf[qs][0], fz);
        st[k4][qs] = MFMA32(a1, qf[qs][1], t0);
      }
    }
    // causal mask (only tiles overlapping the diagonal)
    if (tb + 63 > q0w) {
#pragma unroll
      for (int k4 = 0; k4 < 4; ++k4)
#pragma unroll
        for (int qs = 0; qs < 2; ++qs)
#pragma unroll
          for (int r = 0; r < 4; ++r)
            if (tb + k4 * 16 + 4 * g + r > q0w + qs * 16 + c) st[k4][qs][r] = -1e30f;
    }
    // ---- online softmax (scale 0.125 folded into exp) ----
    bf16x8 pa[2][2];
#pragma unroll
    for (int qs = 0; qs < 2; ++qs) {
      float mx = -1e30f;
#pragma unroll
      for (int k4 = 0; k4 < 4; ++k4)
#pragma unroll
        for (int r = 0; r < 4; ++r) mx = fmaxf(mx, st[k4][qs][r]);
      mx = fmaxf(mx, __shfl_xor(mx, 16));
      mx = fmaxf(mx, __shfl_xor(mx, 32));
      float m_new = fmaxf(m[qs], mx);
      float resc = __expf((m[qs] - m_new) * 0.125f);
      float mh = m_new * 0.125f;
      m[qs] = m_new;
      float rb0 = __shfl(resc, 4 * g + 0);
      float rb1 = __shfl(resc, 4 * g + 1);
      float rb2 = __shfl(resc, 4 * g + 2);
      float rb3 = __shfl(resc, 4 * g + 3);
#pragma unroll
      for (int c4 = 0; c4 < 4; ++c4) {
        oacc[c4][qs][0] *= rb0; oacc[c4][qs][1] *= rb1;
        oacc[c4][qs][2] *= rb2; oacc[c4][qs][3] *= rb3;
      }
      float rs = 0.f;
#pragma unroll
      for (int k4 = 0; k4 < 4; ++k4)
#pragma unroll
        for (int r = 0; r < 4; ++r) {
          float e = __expf(__builtin_fmaf(st[k4][qs][r], 0.125f, -mh));
          st[k4][qs][r] = e;
          rs += e;
        }
      rs += __shfl_xor(rs, 16);
      rs += __shfl_xor(rs, 32);
      l[qs] = l[qs] * resc + rs;
#pragma unroll
      for (int ks = 0; ks < 2; ++ks)
#pragma unroll
        for (int j = 0; j < 8; ++j)
          pa[qs][ks][j] = (short)f2bf(st[ks * 2 + (j >> 2)][qs][j & 3]);
    }
    // ---- PV: O[q][hd] += P[q][t] V[t][hd], V read from swizzled Vs ----
#pragma unroll
    for (int c4 = 0; c4 < 4; ++c4) {
      int row = c4 * 16 + c;
      int rx = row & 7;
#pragma unroll
      for (int ks = 0; ks < 2; ++ks) {
        int e0 = ks * 32 + 4 * g;
        int e1 = e0 + 16;
        int s0 = ((((e0 >> 3) ^ rx)) << 3) | (e0 & 7);
        int s1 = ((((e1 >> 3) ^ rx)) << 3) | (e1 & 7);
        bf16x4 v0 = *(const bf16x4*)&Vs[row * 64 + s0];
        bf16x4 v1 = *(const bf16x4*)&Vs[row * 64 + s1];
        bf16x8 vf;
        vf[0] = v0[0]; vf[1] = v0[1]; vf[2] = v0[2]; vf[3] = v0[3];
        vf[4] = v1[0]; vf[5] = v1[1]; vf[6] = v1[2]; vf[7] = v1[3];
#pragma unroll
        for (int qs = 0; qs < 2; ++qs)
          oacc[c4][qs] = MFMA32(pa[qs][ks], vf, oacc[c4][qs]);
      }
    }
  }
  // ---- epilogue ----
  int b = bh >> 4, h = bh & 15;
#pragma unroll
  for (int qs = 0; qs < 2; ++qs) {
    float linv = 1.f / l[qs];
    float lb0 = __shfl(linv, 4 * g + 0);
    float lb1 = __shfl(linv, 4 * g + 1);
    float lb2 = __shfl(linv, 4 * g + 2);
    float lb3 = __shfl(linv, 4 * g + 3);
    float lb[4] = {lb0, lb1, lb2, lb3};
    unsigned short* op = attn + ((size_t)b * S_ + q0w + qs * 16) * D_ + h * HD_;
#pragma unroll
    for (int c4 = 0; c4 < 4; ++c4)
#pragma unroll
      for (int r = 0; r < 4; ++r)
        op[(size_t)(4 * g + r) * D_ + c4 * 16 + c] = f2bf(oacc[c4][qs][r] * lb[r]);
  }
}

// ---------- GEMM2: out[8192][1024] = attn @ Wp + bp (fp32 out) ----------
__global__ __launch_bounds__(256) void k_gemm_out(const unsigned short* __restrict__ at,
                                                  const unsigned short* __restrict__ WpT,
                                                  const float* __restrict__ bp,
                                                  float* __restrict__ out) {
  __shared__ __align__(16) unsigned short As[128 * 32];
  __shared__ __align__(16) unsigned short Bs[128 * 32];
  const int K = 1024;
  int tid = threadIdx.x;
  int lane = tid & 63;
  int w = tid >> 6;
  int c = lane & 15, g = lane >> 4;
  int wr = w >> 1, wc = w & 1;
  int m0 = blockIdx.y * 128;
  int n0 = blockIdx.x * 128;
  f32x4 acc[4][4];
#pragma unroll
  for (int m = 0; m < 4; ++m)
#pragma unroll
    for (int n = 0; n < 4; ++n) acc[m][n] = (f32x4){0.f, 0.f, 0.f, 0.f};

  int t0 = tid, t1 = tid + 256;
  const unsigned short* ga0 = at + (size_t)(m0 + (t0 >> 2)) * K + 8 * (t0 & 3);
  const unsigned short* ga1 = at + (size_t)(m0 + (t1 >> 2)) * K + 8 * (t1 & 3);
  const unsigned short* gb0 = WpT + (size_t)(n0 + (t0 >> 2)) * K + 8 * (t0 & 3);
  const unsigned short* gb1 = WpT + (size_t)(n0 + (t1 >> 2)) * K + 8 * (t1 & 3);

  for (int kk = 0; kk < K; kk += 32) {
    __syncthreads();
    gload_lds16(ga0 + kk, &As[t0 * 8]);
    gload_lds16(ga1 + kk, &As[t1 * 8]);
    gload_lds16(gb0 + kk, &Bs[t0 * 8]);
    gload_lds16(gb1 + kk, &Bs[t1 * 8]);
    __syncthreads();
    bf16x8 af[4], bfr[4];
#pragma unroll
    for (int m = 0; m < 4; ++m)
      af[m] = *(const bf16x8*)&As[(wr * 64 + m * 16 + c) * 32 + 8 * g];
#pragma unroll
    for (int n = 0; n < 4; ++n)
      bfr[n] = *(const bf16x8*)&Bs[(wc * 64 + n * 16 + c) * 32 + 8 * g];
#pragma unroll
    for (int m = 0; m < 4; ++m)
#pragma unroll
      for (int n = 0; n < 4; ++n) acc[m][n] = MFMA32(af[m], bfr[n], acc[m][n]);
  }

#pragma unroll
  for (int m = 0; m < 4; ++m)
#pragma unroll
    for (int n = 0; n < 4; ++n)
#pragma unroll
      for (int r = 0; r < 4; ++r) {
        int R = m0 + wr * 64 + m * 16 + 4 * g + r;
        int Cn = n0 + wc * 64 + n * 16 + c;
        out[(size_t)R * D_ + Cn] = acc[m][n][r] + bp[Cn];
      }
}

extern "C" void kernel_launch(void* const* d_in, const int* in_sizes, int n_in,
                              void* d_out, int out_size, void* d_ws, size_t ws_size,
                              hipStream_t stream) {
  const float* x  = (const float*)d_in[0];
  const float* Wq = (const float*)d_in[1];
  const float* Wk = (const float*)d_in[2];
  const float* Wv = (const float*)d_in[3];
  const float* Wp = (const float*)d_in[4];
  const float* bp = (const float*)d_in[5];
  float* out = (float*)d_out;
  char* ws = (char*)d_ws;
  unsigned short* xb  = (unsigned short*)(ws);                       // 16 MB (reused as attn out)
  unsigned short* w1t = (unsigned short*)(ws + (size_t)(16u << 20)); //  6 MB
  unsigned short* wpt = (unsigned short*)(ws + (size_t)(22u << 20)); //  2 MB
  unsigned short* qb  = (unsigned short*)(ws + (size_t)(24u << 20)); // 16 MB
  unsigned short* kb  = (unsigned short*)(ws + (size_t)(40u << 20)); // 16 MB
  unsigned short* vt  = (unsigned short*)(ws + (size_t)(56u << 20)); // 16 MB
  unsigned short* at  = xb;  // xb dead after gemm_qkv; reuse for attention output

  k_cast_x<<<dim3(4096), dim3(256), 0, stream>>>(x, xb);
  k_wqkv_t<<<dim3(16, 16, 3), dim3(256), 0, stream>>>(Wq, Wk, Wv, w1t);
  k_wp_t<<<dim3(16, 16), dim3(256), 0, stream>>>(Wp, wpt);
  k_gemm_qkv<<<dim3(24, 64), dim3(256), 0, stream>>>(xb, w1t, qb, kb, vt);
  k_attn<<<dim3(1024), dim3(256), 0, stream>>>(qb, kb, vt, at);
  k_gemm_out<<<dim3(8, 64), dim3(256), 0, stream>>>(at, wpt, bp, out);
}

// Round 3
// 206.292 us; speedup vs baseline: 3.9159x; 1.2650x over previous
//
#include <hip/hip_runtime.h>
#include <stdint.h>

#define B_  4
#define S_  2048
#define D_  1024
#define H_  16
#define HD_ 64

typedef __attribute__((ext_vector_type(8))) short bf16x8;
typedef __attribute__((ext_vector_type(4))) short bf16x4;
typedef __attribute__((ext_vector_type(4))) float f32x4;

#define MFMA32(a, b, c) __builtin_amdgcn_mfma_f32_16x16x32_bf16(a, b, c, 0, 0, 0)

__device__ __forceinline__ unsigned short f2bf(float f) {
  union { float f; uint32_t u; } cv; cv.f = f;
  uint32_t x = cv.u;
  uint32_t r = (x + 0x7fffu + ((x >> 16) & 1u)) >> 16;  // RNE
  return (unsigned short)r;
}

__device__ __forceinline__ unsigned short f2bf_rz(float f) {
  union { float f; uint32_t u; } cv; cv.f = f;
  return (unsigned short)(cv.u >> 16);  // truncate (P-fragment only)
}

__device__ __forceinline__ void gload_lds16(const unsigned short* g, unsigned short* l) {
  __builtin_amdgcn_global_load_lds((const __attribute__((address_space(1))) void*)g,
                                   (__attribute__((address_space(3))) void*)l, 16, 0, 0);
}

// ---------- prep: x fp32 -> bf16 ----------
__global__ void k_cast_x(const float* __restrict__ x, unsigned short* __restrict__ xb) {
  size_t i = ((size_t)blockIdx.x * 256 + threadIdx.x) * 8;
  float4 a = *(const float4*)(x + i);
  float4 b = *(const float4*)(x + i + 4);
  bf16x8 o;
  o[0] = (short)f2bf(a.x); o[1] = (short)f2bf(a.y);
  o[2] = (short)f2bf(a.z); o[3] = (short)f2bf(a.w);
  o[4] = (short)f2bf(b.x); o[5] = (short)f2bf(b.y);
  o[6] = (short)f2bf(b.z); o[7] = (short)f2bf(b.w);
  *(bf16x8*)(xb + i) = o;
}

// ---------- prep: Wq/Wk/Wv [H,D,HD] -> W1T [3072][1024] (n-major, k-contig) ----------
__global__ void k_wqkv_t(const float* __restrict__ Wq, const float* __restrict__ Wk,
                         const float* __restrict__ Wv, unsigned short* __restrict__ W1T) {
  __shared__ unsigned short tile[64][65];
  const float* W = (blockIdx.z == 0) ? Wq : (blockIdx.z == 1) ? Wk : Wv;
  int h = blockIdx.y;
  int d0 = blockIdx.x * 64;
  int tx = threadIdx.x & 63;
  int tg = threadIdx.x >> 6;
  const float* src = W + (size_t)h * (D_ * HD_) + (size_t)d0 * HD_;
#pragma unroll
  for (int r = 0; r < 16; ++r) {
    int dy = tg * 16 + r;
    tile[tx][dy] = f2bf(src[(size_t)dy * HD_ + tx]);
  }
  __syncthreads();
  unsigned short* dst = W1T + ((size_t)blockIdx.z * 1024 + (size_t)h * 64) * 1024 + d0;
#pragma unroll
  for (int r = 0; r < 16; ++r) {
    int hd = tg * 16 + r;
    dst[(size_t)hd * 1024 + tx] = tile[hd][tx];
  }
}

// ---------- prep: Wp [D][D] -> WpT [n][k] ----------
__global__ void k_wp_t(const float* __restrict__ Wp, unsigned short* __restrict__ WpT) {
  __shared__ unsigned short tile[64][65];
  int n0 = blockIdx.x * 64, k0 = blockIdx.y * 64;
  int tx = threadIdx.x & 63;
  int tg = threadIdx.x >> 6;
#pragma unroll
  for (int r = 0; r < 16; ++r) {
    int ky = tg * 16 + r;
    tile[tx][ky] = f2bf(Wp[(size_t)(k0 + ky) * D_ + n0 + tx]);
  }
  __syncthreads();
#pragma unroll
  for (int r = 0; r < 16; ++r) {
    int ny = tg * 16 + r;
    WpT[(size_t)(n0 + ny) * D_ + k0 + tx] = tile[ny][tx];
  }
}

// ---------- GEMM1: C[8192][3072] = xb @ W1T^T ; scatter-store q(*0.125),k,v_t ----------
__global__ __launch_bounds__(256) void k_gemm_qkv(const unsigned short* __restrict__ xb,
                                                  const unsigned short* __restrict__ W1T,
                                                  unsigned short* __restrict__ qb,
                                                  unsigned short* __restrict__ kb,
                                                  unsigned short* __restrict__ vt) {
  __shared__ __align__(16) unsigned short As[128 * 32];
  __shared__ __align__(16) unsigned short Bs[128 * 32];
  const int K = 1024;
  int tid = threadIdx.x;
  int lane = tid & 63;
  int w = tid >> 6;
  int c = lane & 15, g = lane >> 4;
  int wr = w >> 1, wc = w & 1;
  int m0 = blockIdx.y * 128;
  int n0 = blockIdx.x * 128;
  f32x4 acc[4][4];
#pragma unroll
  for (int m = 0; m < 4; ++m)
#pragma unroll
    for (int n = 0; n < 4; ++n) acc[m][n] = (f32x4){0.f, 0.f, 0.f, 0.f};

  int t0 = tid, t1 = tid + 256;
  const unsigned short* ga0 = xb + (size_t)(m0 + (t0 >> 2)) * K + 8 * (t0 & 3);
  const unsigned short* ga1 = xb + (size_t)(m0 + (t1 >> 2)) * K + 8 * (t1 & 3);
  const unsigned short* gb0 = W1T + (size_t)(n0 + (t0 >> 2)) * K + 8 * (t0 & 3);
  const unsigned short* gb1 = W1T + (size_t)(n0 + (t1 >> 2)) * K + 8 * (t1 & 3);

  for (int kk = 0; kk < K; kk += 32) {
    __syncthreads();
    gload_lds16(ga0 + kk, &As[t0 * 8]);
    gload_lds16(ga1 + kk, &As[t1 * 8]);
    gload_lds16(gb0 + kk, &Bs[t0 * 8]);
    gload_lds16(gb1 + kk, &Bs[t1 * 8]);
    __syncthreads();
    bf16x8 af[4], bfr[4];
#pragma unroll
    for (int m = 0; m < 4; ++m)
      af[m] = *(const bf16x8*)&As[(wr * 64 + m * 16 + c) * 32 + 8 * g];
#pragma unroll
    for (int n = 0; n < 4; ++n)
      bfr[n] = *(const bf16x8*)&Bs[(wc * 64 + n * 16 + c) * 32 + 8 * g];
#pragma unroll
    for (int m = 0; m < 4; ++m)
#pragma unroll
      for (int n = 0; n < 4; ++n) acc[m][n] = MFMA32(af[m], bfr[n], acc[m][n]);
  }

#pragma unroll
  for (int m = 0; m < 4; ++m)
#pragma unroll
    for (int n = 0; n < 4; ++n)
#pragma unroll
      for (int r = 0; r < 4; ++r) {
        int R = m0 + wr * 64 + m * 16 + 4 * g + r;
        int Cn = n0 + wc * 64 + n * 16 + c;
        int qkv = Cn >> 10;
        float a = acc[m][n][r];
        unsigned short v = f2bf(qkv == 0 ? a * 0.125f : a);  // fold attn scale into q
        int h = (Cn >> 6) & 15;
        int hd = Cn & 63;
        int b = R >> 11;
        int s = R & 2047;
        size_t bh = (size_t)(b * 16 + h);
        if (qkv == 0)      qb[(bh * S_ + s) * HD_ + hd] = v;
        else if (qkv == 1) kb[(bh * S_ + s) * HD_ + hd] = v;
        else               vt[(bh * HD_ + hd) * S_ + s] = v;  // V transposed
      }
}

// ---------- attention staging helper: K/V tile -> swizzled LDS (dbuf) ----------
__device__ __forceinline__ void stage_kv(const unsigned short* kp, const unsigned short* vp,
                                         int tb, unsigned short* Ks, unsigned short* Vs,
                                         int tid) {
  int i0 = tid, i1 = tid + 256;
  int r0 = i0 >> 3, ch0 = ((i0 & 7) ^ (r0 & 7)) << 3;  // inverse-swizzled global chunk
  int r1 = i1 >> 3, ch1 = ((i1 & 7) ^ (r1 & 7)) << 3;
  gload_lds16(kp + (size_t)(tb + r0) * HD_ + ch0, &Ks[i0 * 8]);
  gload_lds16(kp + (size_t)(tb + r1) * HD_ + ch1, &Ks[i1 * 8]);
  gload_lds16(vp + (size_t)r0 * S_ + tb + ch0, &Vs[i0 * 8]);
  gload_lds16(vp + (size_t)r1 * S_ + tb + ch1, &Vs[i1 * 8]);
}

// ---------- flash attention v3: paired causal tiles (uniform work), dbuf LDS ----------
__global__ __launch_bounds__(256) void k_attn(const unsigned short* __restrict__ qb,
                                              const unsigned short* __restrict__ kb,
                                              const unsigned short* __restrict__ vt,
                                              unsigned short* __restrict__ attn) {
  __shared__ __align__(16) unsigned short Ks[2][64 * 64];
  __shared__ __align__(16) unsigned short Vs[2][64 * 64];
  int tid = threadIdx.x;
  int lane = tid & 63;
  int w = tid >> 6;
  int c = lane & 15, g = lane >> 4;
  // 512 blocks: XCD x gets bh [8x,8x+8) (all 8 pairs each) -> K/V set 4MB = one L2
  int swz = ((blockIdx.x & 7) << 6) | (blockIdx.x >> 3);
  int bh = swz >> 3;
  int pr = swz & 7;
  const unsigned short* kp = kb + (size_t)bh * S_ * HD_;
  const unsigned short* vp = vt + (size_t)bh * HD_ * S_;
  int b = bh >> 4, h = bh & 15;

  for (int p = 0; p < 2; ++p) {
    int j = p ? (15 - pr) : pr;        // work(j) + work(15-j) = uniform 34 stages
    int q0w = j * 128 + w * 32;
    const unsigned short* qp = qb + ((size_t)bh * S_ + q0w) * HD_;
    bf16x8 qf[2][2];
#pragma unroll
    for (int qs = 0; qs < 2; ++qs)
#pragma unroll
      for (int h2 = 0; h2 < 2; ++h2)
        qf[qs][h2] = *(const bf16x8*)(qp + (size_t)(qs * 16 + c) * HD_ + h2 * 32 + 8 * g);

    const f32x4 fz = {0.f, 0.f, 0.f, 0.f};
    f32x4 oacc[4][2];
#pragma unroll
    for (int c4 = 0; c4 < 4; ++c4)
#pragma unroll
      for (int qs = 0; qs < 2; ++qs) oacc[c4][qs] = fz;
    float m[2] = {-1e30f, -1e30f};
    float l[2] = {0.f, 0.f};

    int nkb = 2 * j + 2;
    int nkw = (q0w + 95) >> 6;

    stage_kv(kp, vp, 0, Ks[0], Vs[0], tid);
    __syncthreads();  // vmcnt(0) drained by compiler before barrier

    for (int kt = 0; kt < nkb; ++kt) {
      int cur = kt & 1;
      if (kt + 1 < nkb) stage_kv(kp, vp, (kt + 1) << 6, Ks[cur ^ 1], Vs[cur ^ 1], tid);
      if (kt < nkw) {
        int tb = kt << 6;
        const unsigned short* KsC = Ks[cur];
        const unsigned short* VsC = Vs[cur];
        // ---- QK^T: S^T[t][q]  (q pre-scaled by 1/8) ----
        f32x4 st[4][2];
#pragma unroll
        for (int k4 = 0; k4 < 4; ++k4) {
          int row = k4 * 16 + c;
          int rx = row & 7;
          bf16x8 a0 = *(const bf16x8*)&KsC[row * 64 + ((g ^ rx) << 3)];
          bf16x8 a1 = *(const bf16x8*)&KsC[row * 64 + (((4 + g) ^ rx) << 3)];
#pragma unroll
          for (int qs = 0; qs < 2; ++qs) {
            f32x4 t0 = MFMA32(a0, qf[qs][0], fz);
            st[k4][qs] = MFMA32(a1, qf[qs][1], t0);
          }
        }
        if (tb + 63 > q0w) {  // causal mask near diagonal
#pragma unroll
          for (int k4 = 0; k4 < 4; ++k4)
#pragma unroll
            for (int qs = 0; qs < 2; ++qs)
#pragma unroll
              for (int r = 0; r < 4; ++r)
                if (tb + k4 * 16 + 4 * g + r > q0w + qs * 16 + c) st[k4][qs][r] = -1e30f;
        }
        // ---- online softmax with defer-max ----
        bf16x8 pa[2][2];
#pragma unroll
        for (int qs = 0; qs < 2; ++qs) {
          float mx = -1e30f;
#pragma unroll
          for (int k4 = 0; k4 < 4; ++k4)
#pragma unroll
            for (int r = 0; r < 4; ++r) mx = fmaxf(mx, st[k4][qs][r]);
          mx = fmaxf(mx, __shfl_xor(mx, 16));
          mx = fmaxf(mx, __shfl_xor(mx, 32));
          if (!__all(mx - m[qs] <= 8.f)) {  // rescale only on real max growth
            float m_new = fmaxf(m[qs], mx);
            float resc = __expf(m[qs] - m_new);
            m[qs] = m_new;
            float rb0 = __shfl(resc, 4 * g + 0);
            float rb1 = __shfl(resc, 4 * g + 1);
            float rb2 = __shfl(resc, 4 * g + 2);
            float rb3 = __shfl(resc, 4 * g + 3);
#pragma unroll
            for (int c4 = 0; c4 < 4; ++c4) {
              oacc[c4][qs][0] *= rb0; oacc[c4][qs][1] *= rb1;
              oacc[c4][qs][2] *= rb2; oacc[c4][qs][3] *= rb3;
            }
            l[qs] *= resc;
          }
          float mh = m[qs];
          float rs = 0.f;
#pragma unroll
          for (int k4 = 0; k4 < 4; ++k4)
#pragma unroll
            for (int r = 0; r < 4; ++r) {
              float e = __expf(st[k4][qs][r] - mh);
              st[k4][qs][r] = e;
              rs += e;
            }
          rs += __shfl_xor(rs, 16);
          rs += __shfl_xor(rs, 32);
          l[qs] += rs;
#pragma unroll
          for (int ks = 0; ks < 2; ++ks)
#pragma unroll
            for (int jj = 0; jj < 8; ++jj)
              pa[qs][ks][jj] = (short)f2bf_rz(st[ks * 2 + (jj >> 2)][qs][jj & 3]);
        }
        // ---- PV ----
#pragma unroll
        for (int c4 = 0; c4 < 4; ++c4) {
          int row = c4 * 16 + c;
          int rx = row & 7;
#pragma unroll
          for (int ks = 0; ks < 2; ++ks) {
            int e0 = ks * 32 + 4 * g;
            int e1 = e0 + 16;
            int s0 = (((e0 >> 3) ^ rx) << 3) | (e0 & 7);
            int s1 = (((e1 >> 3) ^ rx) << 3) | (e1 & 7);
            bf16x4 v0 = *(const bf16x4*)&VsC[row * 64 + s0];
            bf16x4 v1 = *(const bf16x4*)&VsC[row * 64 + s1];
            bf16x8 vf;
            vf[0] = v0[0]; vf[1] = v0[1]; vf[2] = v0[2]; vf[3] = v0[3];
            vf[4] = v1[0]; vf[5] = v1[1]; vf[6] = v1[2]; vf[7] = v1[3];
#pragma unroll
            for (int qs = 0; qs < 2; ++qs)
              oacc[c4][qs] = MFMA32(pa[qs][ks], vf, oacc[c4][qs]);
          }
        }
      }
      __syncthreads();
    }
    // ---- epilogue (per phase) ----
#pragma unroll
    for (int qs = 0; qs < 2; ++qs) {
      float linv = 1.f / l[qs];
      float lb0 = __shfl(linv, 4 * g + 0);
      float lb1 = __shfl(linv, 4 * g + 1);
      float lb2 = __shfl(linv, 4 * g + 2);
      float lb3 = __shfl(linv, 4 * g + 3);
      float lb[4] = {lb0, lb1, lb2, lb3};
      unsigned short* op = attn + ((size_t)b * S_ + q0w + qs * 16) * D_ + h * HD_;
#pragma unroll
      for (int c4 = 0; c4 < 4; ++c4)
#pragma unroll
        for (int r = 0; r < 4; ++r)
          op[(size_t)(4 * g + r) * D_ + c4 * 16 + c] = f2bf(oacc[c4][qs][r] * lb[r]);
    }
  }
}

// ---------- GEMM2: out[8192][1024] = attn @ Wp + bp (fp32 out) ----------
__global__ __launch_bounds__(256) void k_gemm_out(const unsigned short* __restrict__ at,
                                                  const unsigned short* __restrict__ WpT,
                                                  const float* __restrict__ bp,
                                                  float* __restrict__ out) {
  __shared__ __align__(16) unsigned short As[128 * 32];
  __shared__ __align__(16) unsigned short Bs[128 * 32];
  const int K = 1024;
  int tid = threadIdx.x;
  int lane = tid & 63;
  int w = tid >> 6;
  int c = lane & 15, g = lane >> 4;
  int wr = w >> 1, wc = w & 1;
  int m0 = blockIdx.y * 128;
  int n0 = blockIdx.x * 128;
  f32x4 acc[4][4];
#pragma unroll
  for (int m = 0; m < 4; ++m)
#pragma unroll
    for (int n = 0; n < 4; ++n) acc[m][n] = (f32x4){0.f, 0.f, 0.f, 0.f};

  int t0 = tid, t1 = tid + 256;
  const unsigned short* ga0 = at + (size_t)(m0 + (t0 >> 2)) * K + 8 * (t0 & 3);
  const unsigned short* ga1 = at + (size_t)(m0 + (t1 >> 2)) * K + 8 * (t1 & 3);
  const unsigned short* gb0 = WpT + (size_t)(n0 + (t0 >> 2)) * K + 8 * (t0 & 3);
  const unsigned short* gb1 = WpT + (size_t)(n0 + (t1 >> 2)) * K + 8 * (t1 & 3);

  for (int kk = 0; kk < K; kk += 32) {
    __syncthreads();
    gload_lds16(ga0 + kk, &As[t0 * 8]);
    gload_lds16(ga1 + kk, &As[t1 * 8]);
    gload_lds16(gb0 + kk, &Bs[t0 * 8]);
    gload_lds16(gb1 + kk, &Bs[t1 * 8]);
    __syncthreads();
    bf16x8 af[4], bfr[4];
#pragma unroll
    for (int m = 0; m < 4; ++m)
      af[m] = *(const bf16x8*)&As[(wr * 64 + m * 16 + c) * 32 + 8 * g];
#pragma unroll
    for (int n = 0; n < 4; ++n)
      bfr[n] = *(const bf16x8*)&Bs[(wc * 64 + n * 16 + c) * 32 + 8 * g];
#pragma unroll
    for (int m = 0; m < 4; ++m)
#pragma unroll
      for (int n = 0; n < 4; ++n) acc[m][n] = MFMA32(af[m], bfr[n], acc[m][n]);
  }

#pragma unroll
  for (int m = 0; m < 4; ++m)
#pragma unroll
    for (int n = 0; n < 4; ++n)
#pragma unroll
      for (int r = 0; r < 4; ++r) {
        int R = m0 + wr * 64 + m * 16 + 4 * g + r;
        int Cn = n0 + wc * 64 + n * 16 + c;
        out[(size_t)R * D_ + Cn] = acc[m][n][r] + bp[Cn];
      }
}

extern "C" void kernel_launch(void* const* d_in, const int* in_sizes, int n_in,
                              void* d_out, int out_size, void* d_ws, size_t ws_size,
                              hipStream_t stream) {
  const float* x  = (const float*)d_in[0];
  const float* Wq = (const float*)d_in[1];
  const float* Wk = (const float*)d_in[2];
  const float* Wv = (const float*)d_in[3];
  const float* Wp = (const float*)d_in[4];
  const float* bp = (const float*)d_in[5];
  float* out = (float*)d_out;
  char* ws = (char*)d_ws;
  unsigned short* xb  = (unsigned short*)(ws);                       // 16 MB (reused as attn out)
  unsigned short* w1t = (unsigned short*)(ws + (size_t)(16u << 20)); //  6 MB
  unsigned short* wpt = (unsigned short*)(ws + (size_t)(22u << 20)); //  2 MB
  unsigned short* qb  = (unsigned short*)(ws + (size_t)(24u << 20)); // 16 MB
  unsigned short* kb  = (unsigned short*)(ws + (size_t)(40u << 20)); // 16 MB
  unsigned short* vt  = (unsigned short*)(ws + (size_t)(56u << 20)); // 16 MB
  unsigned short* at  = xb;  // xb dead after gemm_qkv; reuse for attention output

  k_cast_x<<<dim3(4096), dim3(256), 0, stream>>>(x, xb);
  k_wqkv_t<<<dim3(16, 16, 3), dim3(256), 0, stream>>>(Wq, Wk, Wv, w1t);
  k_wp_t<<<dim3(16, 16), dim3(256), 0, stream>>>(Wp, wpt);
  k_gemm_qkv<<<dim3(24, 64), dim3(256), 0, stream>>>(xb, w1t, qb, kb, vt);
  k_attn<<<dim3(512), dim3(256), 0, stream>>>(qb, kb, vt, at);
  k_gemm_out<<<dim3(8, 64), dim3(256), 0, stream>>>(at, wpt, bp, out);
}

// Round 4
// 191.303 us; speedup vs baseline: 4.2227x; 1.0784x over previous
//
#include <hip/hip_runtime.h>
#include <stdint.h>

#define B_  4
#define S_  2048
#define D_  1024
#define H_  16
#define HD_ 64

typedef __attribute__((ext_vector_type(8))) short bf16x8;
typedef __attribute__((ext_vector_type(4))) short bf16x4;
typedef __attribute__((ext_vector_type(4))) float f32x4;

#define MFMA32(a, b, c) __builtin_amdgcn_mfma_f32_16x16x32_bf16(a, b, c, 0, 0, 0)

__device__ __forceinline__ unsigned short f2bf(float f) {
  union { float f; uint32_t u; } cv; cv.f = f;
  uint32_t x = cv.u;
  uint32_t r = (x + 0x7fffu + ((x >> 16) & 1u)) >> 16;  // RNE
  return (unsigned short)r;
}

__device__ __forceinline__ unsigned short f2bf_rz(float f) {
  union { float f; uint32_t u; } cv; cv.f = f;
  return (unsigned short)(cv.u >> 16);  // truncate (P-fragment only)
}

__device__ __forceinline__ void gload_lds16(const unsigned short* g, unsigned short* l) {
  __builtin_amdgcn_global_load_lds((const __attribute__((address_space(1))) void*)g,
                                   (__attribute__((address_space(3))) void*)l, 16, 0, 0);
}

// ---------- prep: x fp32 -> bf16 ----------
__global__ void k_cast_x(const float* __restrict__ x, unsigned short* __restrict__ xb) {
  size_t i = ((size_t)blockIdx.x * 256 + threadIdx.x) * 8;
  float4 a = *(const float4*)(x + i);
  float4 b = *(const float4*)(x + i + 4);
  bf16x8 o;
  o[0] = (short)f2bf(a.x); o[1] = (short)f2bf(a.y);
  o[2] = (short)f2bf(a.z); o[3] = (short)f2bf(a.w);
  o[4] = (short)f2bf(b.x); o[5] = (short)f2bf(b.y);
  o[6] = (short)f2bf(b.z); o[7] = (short)f2bf(b.w);
  *(bf16x8*)(xb + i) = o;
}

// ---------- prep: Wq/Wk/Wv [H,D,HD] -> W1T [3072][1024] (n-major, k-contig) ----------
__global__ void k_wqkv_t(const float* __restrict__ Wq, const float* __restrict__ Wk,
                         const float* __restrict__ Wv, unsigned short* __restrict__ W1T) {
  __shared__ unsigned short tile[64][65];
  const float* W = (blockIdx.z == 0) ? Wq : (blockIdx.z == 1) ? Wk : Wv;
  int h = blockIdx.y;
  int d0 = blockIdx.x * 64;
  int tx = threadIdx.x & 63;
  int tg = threadIdx.x >> 6;
  const float* src = W + (size_t)h * (D_ * HD_) + (size_t)d0 * HD_;
#pragma unroll
  for (int r = 0; r < 16; ++r) {
    int dy = tg * 16 + r;
    tile[tx][dy] = f2bf(src[(size_t)dy * HD_ + tx]);
  }
  __syncthreads();
  unsigned short* dst = W1T + ((size_t)blockIdx.z * 1024 + (size_t)h * 64) * 1024 + d0;
#pragma unroll
  for (int r = 0; r < 16; ++r) {
    int hd = tg * 16 + r;
    dst[(size_t)hd * 1024 + tx] = tile[hd][tx];
  }
}

// ---------- prep: Wp [D][D] -> WpT [n][k] ----------
__global__ void k_wp_t(const float* __restrict__ Wp, unsigned short* __restrict__ WpT) {
  __shared__ unsigned short tile[64][65];
  int n0 = blockIdx.x * 64, k0 = blockIdx.y * 64;
  int tx = threadIdx.x & 63;
  int tg = threadIdx.x >> 6;
#pragma unroll
  for (int r = 0; r < 16; ++r) {
    int ky = tg * 16 + r;
    tile[tx][ky] = f2bf(Wp[(size_t)(k0 + ky) * D_ + n0 + tx]);
  }
  __syncthreads();
#pragma unroll
  for (int r = 0; r < 16; ++r) {
    int ny = tg * 16 + r;
    WpT[(size_t)(n0 + ny) * D_ + k0 + tx] = tile[ny][tx];
  }
}

// ---------- GEMM1: C[8192][3072] = xb @ W1T^T ; q(*0.125)/k direct, v via LDS transpose ----------
__global__ __launch_bounds__(256) void k_gemm_qkv(const unsigned short* __restrict__ xb,
                                                  const unsigned short* __restrict__ W1T,
                                                  unsigned short* __restrict__ qb,
                                                  unsigned short* __restrict__ kb,
                                                  unsigned short* __restrict__ vt) {
  // lds: K-loop staging As[4096] Bs[4096]; v-epilogue reuses as [128 cols][136] transpose buf
  __shared__ __align__(16) unsigned short lds[128 * 136];
  unsigned short* As = lds;
  unsigned short* Bs = lds + 4096;
  const int K = 1024;
  int tid = threadIdx.x;
  int lane = tid & 63;
  int w = tid >> 6;
  int c = lane & 15, g = lane >> 4;
  int wr = w >> 1, wc = w & 1;
  // T1 XCD-aware swizzle (nwg = 24*64 = 1536, %8==0)
  int nwg = gridDim.x * gridDim.y;
  int bid = blockIdx.y * gridDim.x + blockIdx.x;
  int swzb = (bid & 7) * (nwg >> 3) + (bid >> 3);
  int bx = swzb % gridDim.x, by = swzb / gridDim.x;
  int m0 = by * 128;
  int n0 = bx * 128;
  f32x4 acc[4][4];
#pragma unroll
  for (int m = 0; m < 4; ++m)
#pragma unroll
    for (int n = 0; n < 4; ++n) acc[m][n] = (f32x4){0.f, 0.f, 0.f, 0.f};

  int t0 = tid, t1 = tid + 256;
  const unsigned short* ga0 = xb + (size_t)(m0 + (t0 >> 2)) * K + 8 * (t0 & 3);
  const unsigned short* ga1 = xb + (size_t)(m0 + (t1 >> 2)) * K + 8 * (t1 & 3);
  const unsigned short* gb0 = W1T + (size_t)(n0 + (t0 >> 2)) * K + 8 * (t0 & 3);
  const unsigned short* gb1 = W1T + (size_t)(n0 + (t1 >> 2)) * K + 8 * (t1 & 3);

  for (int kk = 0; kk < K; kk += 32) {
    __syncthreads();
    gload_lds16(ga0 + kk, &As[t0 * 8]);
    gload_lds16(ga1 + kk, &As[t1 * 8]);
    gload_lds16(gb0 + kk, &Bs[t0 * 8]);
    gload_lds16(gb1 + kk, &Bs[t1 * 8]);
    __syncthreads();
    bf16x8 af[4], bfr[4];
#pragma unroll
    for (int m = 0; m < 4; ++m)
      af[m] = *(const bf16x8*)&As[(wr * 64 + m * 16 + c) * 32 + 8 * g];
#pragma unroll
    for (int n = 0; n < 4; ++n)
      bfr[n] = *(const bf16x8*)&Bs[(wc * 64 + n * 16 + c) * 32 + 8 * g];
#pragma unroll
    for (int m = 0; m < 4; ++m)
#pragma unroll
      for (int n = 0; n < 4; ++n) acc[m][n] = MFMA32(af[m], bfr[n], acc[m][n]);
  }

  int qkv = n0 >> 10;  // uniform per block (tile width 128 never crosses a 1024 boundary)
  int b = m0 >> 11;
  int s0 = m0 & 2047;
  if (qkv < 2) {
    unsigned short* dst = (qkv == 0) ? qb : kb;
    float sc = (qkv == 0) ? 0.125f : 1.0f;  // fold attn scale into q
#pragma unroll
    for (int m = 0; m < 4; ++m)
#pragma unroll
      for (int n = 0; n < 4; ++n)
#pragma unroll
        for (int r = 0; r < 4; ++r) {
          int s = s0 + wr * 64 + m * 16 + 4 * g + r;
          int Cn = n0 + wc * 64 + n * 16 + c;
          int h = (Cn >> 6) & 15;
          int hd = Cn & 63;
          dst[((size_t)(b * 16 + h) * S_ + s) * HD_ + hd] = f2bf(acc[m][n][r] * sc);
        }
  } else {
    // v: transpose through LDS, then 16B-chunk stores along s
    __syncthreads();  // K-loop LDS reads done before overwrite
#pragma unroll
    for (int m = 0; m < 4; ++m)
#pragma unroll
      for (int n = 0; n < 4; ++n) {
        int col = wc * 64 + n * 16 + c;          // local n (-> hd)
        int row4 = wr * 64 + m * 16 + 4 * g;     // local m (-> s), 4 consecutive
        bf16x4 pk;
        pk[0] = (short)f2bf(acc[m][n][0]);
        pk[1] = (short)f2bf(acc[m][n][1]);
        pk[2] = (short)f2bf(acc[m][n][2]);
        pk[3] = (short)f2bf(acc[m][n][3]);
        *(bf16x4*)&lds[col * 136 + row4] = pk;   // ds_write_b64, 8B-aligned (136*2%8==0)
      }
    __syncthreads();
    int col = tid >> 1;
    int sh = (tid & 1) * 64;
    int Cn = n0 + col;
    int h = (Cn >> 6) & 15;
    int hd = Cn & 63;
    unsigned short* dst = vt + ((size_t)(b * 16 + h) * HD_ + hd) * S_ + s0 + sh;
#pragma unroll
    for (int j = 0; j < 8; ++j)
      *(bf16x8*)(dst + 8 * j) = *(const bf16x8*)&lds[col * 136 + sh + 8 * j];
  }
}

// ---------- attention staging helper: K/V tile -> swizzled LDS (dbuf) ----------
__device__ __forceinline__ void stage_kv(const unsigned short* kp, const unsigned short* vp,
                                         int tb, unsigned short* Ks, unsigned short* Vs,
                                         int tid) {
  int i0 = tid, i1 = tid + 256;
  int r0 = i0 >> 3, ch0 = ((i0 & 7) ^ (r0 & 7)) << 3;  // inverse-swizzled global chunk
  int r1 = i1 >> 3, ch1 = ((i1 & 7) ^ (r1 & 7)) << 3;
  gload_lds16(kp + (size_t)(tb + r0) * HD_ + ch0, &Ks[i0 * 8]);
  gload_lds16(kp + (size_t)(tb + r1) * HD_ + ch1, &Ks[i1 * 8]);
  gload_lds16(vp + (size_t)r0 * S_ + tb + ch0, &Vs[i0 * 8]);
  gload_lds16(vp + (size_t)r1 * S_ + tb + ch1, &Vs[i1 * 8]);
}

// ---------- flash attention v3: paired causal tiles (uniform work), dbuf LDS ----------
__global__ __launch_bounds__(256) void k_attn(const unsigned short* __restrict__ qb,
                                              const unsigned short* __restrict__ kb,
                                              const unsigned short* __restrict__ vt,
                                              unsigned short* __restrict__ attn) {
  __shared__ __align__(16) unsigned short Ks[2][64 * 64];
  __shared__ __align__(16) unsigned short Vs[2][64 * 64];
  int tid = threadIdx.x;
  int lane = tid & 63;
  int w = tid >> 6;
  int c = lane & 15, g = lane >> 4;
  // 512 blocks: XCD x gets bh [8x,8x+8) (all 8 pairs each) -> K/V set 4MB = one L2
  int swz = ((blockIdx.x & 7) << 6) | (blockIdx.x >> 3);
  int bh = swz >> 3;
  int pr = swz & 7;
  const unsigned short* kp = kb + (size_t)bh * S_ * HD_;
  const unsigned short* vp = vt + (size_t)bh * HD_ * S_;
  int b = bh >> 4, h = bh & 15;

  for (int p = 0; p < 2; ++p) {
    int j = p ? (15 - pr) : pr;        // work(j) + work(15-j) = uniform 34 stages
    int q0w = j * 128 + w * 32;
    const unsigned short* qp = qb + ((size_t)bh * S_ + q0w) * HD_;
    bf16x8 qf[2][2];
#pragma unroll
    for (int qs = 0; qs < 2; ++qs)
#pragma unroll
      for (int h2 = 0; h2 < 2; ++h2)
        qf[qs][h2] = *(const bf16x8*)(qp + (size_t)(qs * 16 + c) * HD_ + h2 * 32 + 8 * g);

    const f32x4 fz = {0.f, 0.f, 0.f, 0.f};
    f32x4 oacc[4][2];
#pragma unroll
    for (int c4 = 0; c4 < 4; ++c4)
#pragma unroll
      for (int qs = 0; qs < 2; ++qs) oacc[c4][qs] = fz;
    float m[2] = {-1e30f, -1e30f};
    float l[2] = {0.f, 0.f};

    int nkb = 2 * j + 2;
    int nkw = (q0w + 95) >> 6;

    stage_kv(kp, vp, 0, Ks[0], Vs[0], tid);
    __syncthreads();

    for (int kt = 0; kt < nkb; ++kt) {
      int cur = kt & 1;
      if (kt + 1 < nkb) stage_kv(kp, vp, (kt + 1) << 6, Ks[cur ^ 1], Vs[cur ^ 1], tid);
      if (kt < nkw) {
        int tb = kt << 6;
        const unsigned short* KsC = Ks[cur];
        const unsigned short* VsC = Vs[cur];
        // ---- QK^T: S^T[t][q]  (q pre-scaled by 1/8) ----
        f32x4 st[4][2];
#pragma unroll
        for (int k4 = 0; k4 < 4; ++k4) {
          int row = k4 * 16 + c;
          int rx = row & 7;
          bf16x8 a0 = *(const bf16x8*)&KsC[row * 64 + ((g ^ rx) << 3)];
          bf16x8 a1 = *(const bf16x8*)&KsC[row * 64 + (((4 + g) ^ rx) << 3)];
#pragma unroll
          for (int qs = 0; qs < 2; ++qs) {
            f32x4 t0 = MFMA32(a0, qf[qs][0], fz);
            st[k4][qs] = MFMA32(a1, qf[qs][1], t0);
          }
        }
        if (tb + 63 > q0w) {  // causal mask near diagonal
#pragma unroll
          for (int k4 = 0; k4 < 4; ++k4)
#pragma unroll
            for (int qs = 0; qs < 2; ++qs)
#pragma unroll
              for (int r = 0; r < 4; ++r)
                if (tb + k4 * 16 + 4 * g + r > q0w + qs * 16 + c) st[k4][qs][r] = -1e30f;
        }
        // ---- online softmax with defer-max ----
        bf16x8 pa[2][2];
#pragma unroll
        for (int qs = 0; qs < 2; ++qs) {
          float mx = -1e30f;
#pragma unroll
          for (int k4 = 0; k4 < 4; ++k4)
#pragma unroll
            for (int r = 0; r < 4; ++r) mx = fmaxf(mx, st[k4][qs][r]);
          mx = fmaxf(mx, __shfl_xor(mx, 16));
          mx = fmaxf(mx, __shfl_xor(mx, 32));
          if (!__all(mx - m[qs] <= 8.f)) {  // rescale only on real max growth
            float m_new = fmaxf(m[qs], mx);
            float resc = __expf(m[qs] - m_new);
            m[qs] = m_new;
            float rb0 = __shfl(resc, 4 * g + 0);
            float rb1 = __shfl(resc, 4 * g + 1);
            float rb2 = __shfl(resc, 4 * g + 2);
            float rb3 = __shfl(resc, 4 * g + 3);
#pragma unroll
            for (int c4 = 0; c4 < 4; ++c4) {
              oacc[c4][qs][0] *= rb0; oacc[c4][qs][1] *= rb1;
              oacc[c4][qs][2] *= rb2; oacc[c4][qs][3] *= rb3;
            }
            l[qs] *= resc;
          }
          float mh = m[qs];
          float rs = 0.f;
#pragma unroll
          for (int k4 = 0; k4 < 4; ++k4)
#pragma unroll
            for (int r = 0; r < 4; ++r) {
              float e = __expf(st[k4][qs][r] - mh);
              st[k4][qs][r] = e;
              rs += e;
            }
          rs += __shfl_xor(rs, 16);
          rs += __shfl_xor(rs, 32);
          l[qs] += rs;
#pragma unroll
          for (int ks = 0; ks < 2; ++ks)
#pragma unroll
            for (int jj = 0; jj < 8; ++jj)
              pa[qs][ks][jj] = (short)f2bf_rz(st[ks * 2 + (jj >> 2)][qs][jj & 3]);
        }
        // ---- PV ----
#pragma unroll
        for (int c4 = 0; c4 < 4; ++c4) {
          int row = c4 * 16 + c;
          int rx = row & 7;
#pragma unroll
          for (int ks = 0; ks < 2; ++ks) {
            int e0 = ks * 32 + 4 * g;
            int e1 = e0 + 16;
            int s0 = (((e0 >> 3) ^ rx) << 3) | (e0 & 7);
            int s1 = (((e1 >> 3) ^ rx) << 3) | (e1 & 7);
            bf16x4 v0 = *(const bf16x4*)&VsC[row * 64 + s0];
            bf16x4 v1 = *(const bf16x4*)&VsC[row * 64 + s1];
            bf16x8 vf;
            vf[0] = v0[0]; vf[1] = v0[1]; vf[2] = v0[2]; vf[3] = v0[3];
            vf[4] = v1[0]; vf[5] = v1[1]; vf[6] = v1[2]; vf[7] = v1[3];
#pragma unroll
            for (int qs = 0; qs < 2; ++qs)
              oacc[c4][qs] = MFMA32(pa[qs][ks], vf, oacc[c4][qs]);
          }
        }
      }
      __syncthreads();
    }
    // ---- epilogue (per phase) ----
#pragma unroll
    for (int qs = 0; qs < 2; ++qs) {
      float linv = 1.f / l[qs];
      float lb0 = __shfl(linv, 4 * g + 0);
      float lb1 = __shfl(linv, 4 * g + 1);
      float lb2 = __shfl(linv, 4 * g + 2);
      float lb3 = __shfl(linv, 4 * g + 3);
      float lb[4] = {lb0, lb1, lb2, lb3};
      unsigned short* op = attn + ((size_t)b * S_ + q0w + qs * 16) * D_ + h * HD_;
#pragma unroll
      for (int c4 = 0; c4 < 4; ++c4)
#pragma unroll
        for (int r = 0; r < 4; ++r)
          op[(size_t)(4 * g + r) * D_ + c4 * 16 + c] = f2bf(oacc[c4][qs][r] * lb[r]);
    }
  }
}

// ---------- GEMM2: out[8192][1024] = attn @ Wp + bp (fp32 out) ----------
__global__ __launch_bounds__(256) void k_gemm_out(const unsigned short* __restrict__ at,
                                                  const unsigned short* __restrict__ WpT,
                                                  const float* __restrict__ bp,
                                                  float* __restrict__ out) {
  __shared__ __align__(16) unsigned short As[128 * 32];
  __shared__ __align__(16) unsigned short Bs[128 * 32];
  const int K = 1024;
  int tid = threadIdx.x;
  int lane = tid & 63;
  int w = tid >> 6;
  int c = lane & 15, g = lane >> 4;
  int wr = w >> 1, wc = w & 1;
  // T1 XCD-aware swizzle (nwg = 8*64 = 512, %8==0)
  int nwg = gridDim.x * gridDim.y;
  int bid = blockIdx.y * gridDim.x + blockIdx.x;
  int swzb = (bid & 7) * (nwg >> 3) + (bid >> 3);
  int bx = swzb % gridDim.x, by = swzb / gridDim.x;
  int m0 = by * 128;
  int n0 = bx * 128;
  f32x4 acc[4][4];
#pragma unroll
  for (int m = 0; m < 4; ++m)
#pragma unroll
    for (int n = 0; n < 4; ++n) acc[m][n] = (f32x4){0.f, 0.f, 0.f, 0.f};

  int t0 = tid, t1 = tid + 256;
  const unsigned short* ga0 = at + (size_t)(m0 + (t0 >> 2)) * K + 8 * (t0 & 3);
  const unsigned short* ga1 = at + (size_t)(m0 + (t1 >> 2)) * K + 8 * (t1 & 3);
  const unsigned short* gb0 = WpT + (size_t)(n0 + (t0 >> 2)) * K + 8 * (t0 & 3);
  const unsigned short* gb1 = WpT + (size_t)(n0 + (t1 >> 2)) * K + 8 * (t1 & 3);

  for (int kk = 0; kk < K; kk += 32) {
    __syncthreads();
    gload_lds16(ga0 + kk, &As[t0 * 8]);
    gload_lds16(ga1 + kk, &As[t1 * 8]);
    gload_lds16(gb0 + kk, &Bs[t0 * 8]);
    gload_lds16(gb1 + kk, &Bs[t1 * 8]);
    __syncthreads();
    bf16x8 af[4], bfr[4];
#pragma unroll
    for (int m = 0; m < 4; ++m)
      af[m] = *(const bf16x8*)&As[(wr * 64 + m * 16 + c) * 32 + 8 * g];
#pragma unroll
    for (int n = 0; n < 4; ++n)
      bfr[n] = *(const bf16x8*)&Bs[(wc * 64 + n * 16 + c) * 32 + 8 * g];
#pragma unroll
    for (int m = 0; m < 4; ++m)
#pragma unroll
      for (int n = 0; n < 4; ++n) acc[m][n] = MFMA32(af[m], bfr[n], acc[m][n]);
  }

#pragma unroll
  for (int m = 0; m < 4; ++m)
#pragma unroll
    for (int n = 0; n < 4; ++n)
#pragma unroll
      for (int r = 0; r < 4; ++r) {
        int R = m0 + wr * 64 + m * 16 + 4 * g + r;
        int Cn = n0 + wc * 64 + n * 16 + c;
        out[(size_t)R * D_ + Cn] = acc[m][n][r] + bp[Cn];
      }
}

extern "C" void kernel_launch(void* const* d_in, const int* in_sizes, int n_in,
                              void* d_out, int out_size, void* d_ws, size_t ws_size,
                              hipStream_t stream) {
  const float* x  = (const float*)d_in[0];
  const float* Wq = (const float*)d_in[1];
  const float* Wk = (const float*)d_in[2];
  const float* Wv = (const float*)d_in[3];
  const float* Wp = (const float*)d_in[4];
  const float* bp = (const float*)d_in[5];
  float* out = (float*)d_out;
  char* ws = (char*)d_ws;
  unsigned short* xb  = (unsigned short*)(ws);                       // 16 MB (reused as attn out)
  unsigned short* w1t = (unsigned short*)(ws + (size_t)(16u << 20)); //  6 MB
  unsigned short* wpt = (unsigned short*)(ws + (size_t)(22u << 20)); //  2 MB
  unsigned short* qb  = (unsigned short*)(ws + (size_t)(24u << 20)); // 16 MB
  unsigned short* kb  = (unsigned short*)(ws + (size_t)(40u << 20)); // 16 MB
  unsigned short* vt  = (unsigned short*)(ws + (size_t)(56u << 20)); // 16 MB
  unsigned short* at  = xb;  // xb dead after gemm_qkv; reuse for attention output

  k_cast_x<<<dim3(4096), dim3(256), 0, stream>>>(x, xb);
  k_wqkv_t<<<dim3(16, 16, 3), dim3(256), 0, stream>>>(Wq, Wk, Wv, w1t);
  k_wp_t<<<dim3(16, 16), dim3(256), 0, stream>>>(Wp, wpt);
  k_gemm_qkv<<<dim3(24, 64), dim3(256), 0, stream>>>(xb, w1t, qb, kb, vt);
  k_attn<<<dim3(512), dim3(256), 0, stream>>>(qb, kb, vt, at);
  k_gemm_out<<<dim3(8, 64), dim3(256), 0, stream>>>(at, wpt, bp, out);
}